// Round 11
// baseline (1695.040 us; speedup 1.0000x reference)
//
#include <hip/hip_runtime.h>
#include <hip/hip_bf16.h>
#include <math.h>

// Problem dims (fixed by reference)
#define T_STEPS 512
#define BATCH   64
#define DIN     256
#define HID     1024
#define DOUT    256
#define NBLK    64      // rnn blocks: 4 row-groups x 16 col-groups

typedef __attribute__((ext_vector_type(8))) short    bf16x8;
typedef __attribute__((ext_vector_type(4))) float    f32x4;
typedef __attribute__((ext_vector_type(4))) int      i32x4;
typedef unsigned long long ull;

static __device__ __forceinline__ unsigned short f2bf(float f) {
    union { float f; unsigned u; } v; v.f = f;
    unsigned u = v.u;
    u += 0x7fff + ((u >> 16) & 1);   // round-to-nearest-even
    return (unsigned short)(u >> 16);
}
static __device__ __forceinline__ float bf2f(unsigned short h) {
    union { unsigned u; float f; } v; v.u = ((unsigned)h) << 16; return v.f;
}

// Agent-scope (device-coherent) ops; lower to sc1 (L2-bypass to MALL
// coherence point). Protocol correctness proven R4/R6/R9.
static __device__ __forceinline__ void coh_store8(ull* p, ull v) {
    __hip_atomic_store(p, v, __ATOMIC_RELAXED, __HIP_MEMORY_SCOPE_AGENT);
}
static __device__ __forceinline__ unsigned coh_load4(const unsigned* p) {
    return __hip_atomic_load(p, __ATOMIC_RELAXED, __HIP_MEMORY_SCOPE_AGENT);
}
static __device__ __forceinline__ void coh_store4(unsigned* p, unsigned v) {
    __hip_atomic_store(p, v, __ATOMIC_RELAXED, __HIP_MEMORY_SCOPE_AGENT);
}

// ---------------- x fp32 -> bf16 ----------------
__global__ __launch_bounds__(256) void convert_x(const float* __restrict__ x,
                                                 unsigned short* __restrict__ xb) {
    size_t i = ((size_t)blockIdx.x * 256 + threadIdx.x) * 4;
    float4 v = *(const float4*)(x + i);
    ushort4 o;
    o.x = f2bf(v.x); o.y = f2bf(v.y); o.z = f2bf(v.z); o.w = f2bf(v.w);
    *(ushort4*)(xb + i) = o;
}

// ---------------- persistent recurrence kernel (pre-GEMM fused) ----------------
// 64 blocks x 256 threads. Block bx: c=bx&15 (cols 64c..64c+64), r=bx>>4
// (rows 16r..16r+16). Wave w owns K range [256w..256w+256); Wh slice in REGS.
// h chunks (16B) A-frag layout: unit16 = r*2048 + ks*64 + lkq*16 + m.
// Per step: issue x[t+1] loads (cached, off-path) -> early-start poll (16
// producer wave-flags) -> 8 sc1 dwordx4 h loads (one vmcnt window) -> 32
// h-MFMA -> partials to parity ldsR -> pre[t+1] = x[t+1]@Wx (8 MFMA, Wx frags
// from LDS) into parity ldsPre (wave-private transpose) -> ONE barrier ->
// 4-wave reduce + pre[t] + tanh -> coherent 8B store -> per-wave vmcnt drain
// -> wave flag. h triple-buffered (R9 skew<=2 safety argument unchanged).
__global__ __launch_bounds__(256, 1) void rnn_persistent(const float* __restrict__ Wh,
                                                         const float* __restrict__ Wx,
                                                         const float* __restrict__ bias,
                                                         const unsigned short* __restrict__ xb,
                                                         unsigned short* __restrict__ hbuf,
                                                         unsigned* __restrict__ flags) {
    __shared__ float ldsR[2][4][16 * 68];            // 34816 B: cross-wave partials
    __shared__ float ldsPre[2][4][16 * 20];          // 10240 B: pre tiles (wave-private)
    __shared__ unsigned short ldsWx[4][8][64 * 8];   // 32768 B: Wx B-frags (wave-private)
    const int bx = blockIdx.x;
    const int c = bx & 15, r = bx >> 4;
    const int tid = threadIdx.x;
    const int w = tid >> 6, lane = tid & 63;
    const int l15 = lane & 15, lkq = lane >> 4;
    const int p = (lane >> 4) & 1, q = lane >> 5;
    const int m = l15;

    // One-time: Wh B-fragments (k in wave range, cols 64c..64c+64) -> regs.
    bf16x8 bfr[8][4];
#pragma unroll
    for (int ksl = 0; ksl < 8; ++ksl)
#pragma unroll
        for (int nt = 0; nt < 4; ++nt) {
            union { unsigned short s[8]; bf16x8 h; } u;
            int k0 = w * 256 + ksl * 32 + lkq * 8;
            int col = c * 64 + nt * 16 + l15;
#pragma unroll
            for (int j = 0; j < 8; ++j)
                u.s[j] = f2bf(Wh[(size_t)(k0 + j) * HID + col]);
            bfr[ksl][nt] = u.h;
        }

    // One-time: Wx B-frags for wave w (cols 64c+16w..+16, k 0..256) -> LDS.
    {
        int col = c * 64 + w * 16 + l15;
#pragma unroll
        for (int ksl = 0; ksl < 8; ++ksl) {
            union { unsigned short s[8]; bf16x8 h; } u;
            int k0 = ksl * 32 + lkq * 8;
#pragma unroll
            for (int j = 0; j < 8; ++j)
                u.s[j] = f2bf(Wx[(size_t)(k0 + j) * HID + col]);
            *(bf16x8*)&ldsWx[w][ksl][lane * 8] = u.h;
        }
    }
    const float bb = bias[c * 64 + w * 16 + l15];

    // Bootstrap: pre[0] and pre[1] tiles into ldsPre parity 0 / 1.
#pragma unroll
    for (int tt = 0; tt < 2; ++tt) {
        f32x4 pacc = {};
#pragma unroll
        for (int ksl = 0; ksl < 8; ++ksl) {
            bf16x8 a = *(const bf16x8*)(xb + ((size_t)tt * 64 + 16 * r + l15) * 256 + ksl * 32 + lkq * 8);
            bf16x8 b = *(const bf16x8*)&ldsWx[w][ksl][lane * 8];
            pacc = __builtin_amdgcn_mfma_f32_16x16x32_bf16(a, b, pacc, 0, 0, 0);
        }
#pragma unroll
        for (int reg = 0; reg < 4; ++reg)
            ldsPre[tt][w][(lkq * 4 + reg) * 20 + l15] = pacc[reg] + bb;
    }

    char* hb = (char*)hbuf;               // 3 buffers x 128 KB
    const char* hc = hb + 131072;         // read  at t=1 (h_1)
    char*       hn = hb + 2 * 131072;     // write at t=1 (h_2)
    char*       hx = hb;                  // write at t=2

    // This thread's h-store unit (8B): chunk (ks=2c+(w>>1), lkq=2(w&1)+p, m), half q
    const size_t st_unit8 =
        2 * ((size_t)r * 2048 + (size_t)(2 * c + (w >> 1)) * 64 + (2 * (w & 1) + p) * 16 + m) + q;

    const int myFlag = (bx << 2) + w;
    const int pollIdx = r * 64 + 16 * w + l15;   // 16 wave-flags of 4 producer blocks

    // t = 0: h1 = tanh(pre[0]) (h0 == 0) -> buf1.
    {
        union { ushort4 s; ull u; } hv;
        const float* P = &ldsPre[0][w][m * 20 + 8 * p + 4 * q];
        hv.s.x = f2bf(tanhf(P[0]));
        hv.s.y = f2bf(tanhf(P[1]));
        hv.s.z = f2bf(tanhf(P[2]));
        hv.s.w = f2bf(tanhf(P[3]));
        coh_store8((ull*)(hb + 131072) + st_unit8, hv.u);
        __builtin_amdgcn_fence(__ATOMIC_RELEASE, "workgroup");   // per-wave vmcnt drain
        if (lane == 0) coh_store4(&flags[myFlag], 1u);
    }

    for (int t = 1; t <= 510; ++t) {
        // Issue x[t+1] A-frag loads early (cached; consumed pre-barrier).
        i32x4 xl[8];
        if (t < 510) {
            const unsigned short* xbase = xb + ((size_t)(t + 1) * 64 + 16 * r + l15) * 256 + lkq * 8;
#pragma unroll
            for (int ksl = 0; ksl < 8; ++ksl)
                xl[ksl] = *(const i32x4*)(xbase + ksl * 32);
        }

        // Early-start poll: wave w waits only for its k-range producers.
        {
            const unsigned tt = (unsigned)t;
            for (;;) {
                unsigned v = coh_load4(&flags[pollIdx]);
                if (__ballot(v >= tt) == ~0ull) break;
                __builtin_amdgcn_s_sleep(1);
            }
        }

        // h import: 8 x 16B agent-coherent loads, ALL in flight, one window.
        i32x4 a[8];
        const char* abase = hc + ((size_t)r * 2048 + (size_t)(8 * w) * 64 + lane) * 16;
#pragma unroll
        for (int ksl = 0; ksl < 8; ++ksl)
            asm volatile("global_load_dwordx4 %0, %1, off sc1"
                         : "=v"(a[ksl])
                         : "v"((const void*)(abase + (size_t)ksl * 1024)));
        asm volatile("s_waitcnt vmcnt(0)" ::: "memory");
        __builtin_amdgcn_sched_barrier(0);

        f32x4 acc0 = {}, acc1 = {}, acc2 = {}, acc3 = {};
#pragma unroll
        for (int ksl = 0; ksl < 8; ++ksl) {
            union { i32x4 i; bf16x8 h; } av; av.i = a[ksl];
            acc0 = __builtin_amdgcn_mfma_f32_16x16x32_bf16(av.h, bfr[ksl][0], acc0, 0, 0, 0);
            acc1 = __builtin_amdgcn_mfma_f32_16x16x32_bf16(av.h, bfr[ksl][1], acc1, 0, 0, 0);
            acc2 = __builtin_amdgcn_mfma_f32_16x16x32_bf16(av.h, bfr[ksl][2], acc2, 0, 0, 0);
            acc3 = __builtin_amdgcn_mfma_f32_16x16x32_bf16(av.h, bfr[ksl][3], acc3, 0, 0, 0);
        }

        // Partial sums -> parity LDS (row = lkq*4+reg, col = nt*16+l15).
        float* R = &ldsR[t & 1][w][0];
#pragma unroll
        for (int reg = 0; reg < 4; ++reg) {
            R[(lkq * 4 + reg) * 68 + l15]      = acc0[reg];
            R[(lkq * 4 + reg) * 68 + 16 + l15] = acc1[reg];
            R[(lkq * 4 + reg) * 68 + 32 + l15] = acc2[reg];
            R[(lkq * 4 + reg) * 68 + 48 + l15] = acc3[reg];
        }

        // Fused pre[t+1] = x[t+1] @ Wx + b (dead-zone work, wave-private).
        if (t < 510) {
            f32x4 pacc = {};
#pragma unroll
            for (int ksl = 0; ksl < 8; ++ksl) {
                union { i32x4 i; bf16x8 h; } av; av.i = xl[ksl];
                bf16x8 b = *(const bf16x8*)&ldsWx[w][ksl][lane * 8];
                pacc = __builtin_amdgcn_mfma_f32_16x16x32_bf16(av.h, b, pacc, 0, 0, 0);
            }
#pragma unroll
            for (int reg = 0; reg < 4; ++reg)
                ldsPre[(t + 1) & 1][w][(lkq * 4 + reg) * 20 + l15] = pacc[reg] + bb;
        }

        __syncthreads();   // the ONE barrier per step (cross-wave reduce)

        // Reduce across 4 waves, add pre[t], tanh, pack, coherent 8B store.
        const int coloff = 16 * w + 8 * p + 4 * q;
        f32x4 s;
        s  = *(const f32x4*)&ldsR[t & 1][0][m * 68 + coloff];
        s += *(const f32x4*)&ldsR[t & 1][1][m * 68 + coloff];
        s += *(const f32x4*)&ldsR[t & 1][2][m * 68 + coloff];
        s += *(const f32x4*)&ldsR[t & 1][3][m * 68 + coloff];
        const float* P = &ldsPre[t & 1][w][m * 20 + 8 * p + 4 * q];
        union { ushort4 st; ull u; } hv;
        hv.st.x = f2bf(tanhf(s[0] + P[0]));
        hv.st.y = f2bf(tanhf(s[1] + P[1]));
        hv.st.z = f2bf(tanhf(s[2] + P[2]));
        hv.st.w = f2bf(tanhf(s[3] + P[3]));
        coh_store8((ull*)hn + st_unit8, hv.u);

        __builtin_amdgcn_fence(__ATOMIC_RELEASE, "workgroup");   // per-wave vmcnt drain
        if (t < 510 && lane == 0) coh_store4(&flags[myFlag], (unsigned)(t + 1));

        // rotate triple buffer
        const char* tmp = hc; hc = hn; hn = hx; hx = (char*)tmp;
    }
    // h_511 (== H[-2]) is in buf1; kernel end = implicit device release.
}

// ---------------- y = h_final @ W2 + b2 (h in A-frag chunk layout) ----------
__global__ __launch_bounds__(256) void out_gemm(const unsigned short* __restrict__ hfin,
                                                const float* __restrict__ W2,
                                                const float* __restrict__ b2,
                                                float* __restrict__ out) {
    int b = blockIdx.x;        // batch row, 64
    int j = threadIdx.x;       // out col, 256
    int r = b >> 4, m = b & 15;
    float acc = b2[j];
    for (int ks = 0; ks < 32; ++ks) {
#pragma unroll
        for (int lkq = 0; lkq < 4; ++lkq) {
            const unsigned short* ch =
                hfin + ((size_t)(r * 2048 + ks * 64 + lkq * 16 + m)) * 8;
            int k0 = ks * 32 + lkq * 8;
#pragma unroll
            for (int jj = 0; jj < 8; ++jj)
                acc = fmaf(bf2f(ch[jj]), W2[(size_t)(k0 + jj) * DOUT + j], acc);
        }
    }
    out[(size_t)b * DOUT + j] = acc;
}

extern "C" void kernel_launch(void* const* d_in, const int* in_sizes, int n_in,
                              void* d_out, int out_size, void* d_ws, size_t ws_size,
                              hipStream_t stream) {
    const float* x  = (const float*)d_in[0];
    const float* Wx = (const float*)d_in[1];
    const float* Wh = (const float*)d_in[2];
    const float* b  = (const float*)d_in[3];
    const float* W2 = (const float*)d_in[4];
    const float* b2 = (const float*)d_in[5];
    float* out = (float*)d_out;

    // workspace carve (~17 MB)
    char* ws = (char*)d_ws;
    unsigned*       flags = (unsigned*)ws;                          // 1 KB (256 wave-flags)
    unsigned short* hbuf  = (unsigned short*)(ws + 4096);           // 3 x 128 KB
    unsigned short* xb    = (unsigned short*)(ws + 4096 + 393216);  // 16 MB bf16 x

    (void)hipMemsetAsync(flags, 0, 4096, stream);
    convert_x<<<8192, 256, 0, stream>>>(x, xb);
    rnn_persistent<<<NBLK, 256, 0, stream>>>(Wh, Wx, b, xb, hbuf, flags);
    out_gemm<<<64, 256, 0, stream>>>(hbuf + 65536, W2, b2, out);
}

// Round 12
// 1594.109 us; speedup vs baseline: 1.0633x; 1.0633x over previous
//
#include <hip/hip_runtime.h>
#include <hip/hip_bf16.h>
#include <math.h>

// Problem dims (fixed by reference)
#define T_STEPS 512
#define BATCH   64
#define DIN     256
#define HID     1024
#define DOUT    256
#define NBLK    64      // rnn blocks: 4 row-groups x 16 col-groups

typedef __attribute__((ext_vector_type(8))) short    bf16x8;
typedef __attribute__((ext_vector_type(4))) float    f32x4;
typedef __attribute__((ext_vector_type(4))) int      i32x4;
typedef unsigned long long ull;

static __device__ __forceinline__ unsigned short f2bf(float f) {
    union { float f; unsigned u; } v; v.f = f;
    unsigned u = v.u;
    u += 0x7fff + ((u >> 16) & 1);   // round-to-nearest-even
    return (unsigned short)(u >> 16);
}
static __device__ __forceinline__ float bf2f(unsigned short h) {
    union { unsigned u; float f; } v; v.u = ((unsigned)h) << 16; return v.f;
}

// Agent-scope (device-coherent) ops; lower to sc1 (L2-bypass to MALL
// coherence point). Protocol correctness proven R4/R6/R9.
static __device__ __forceinline__ void coh_store8(ull* p, ull v) {
    __hip_atomic_store(p, v, __ATOMIC_RELAXED, __HIP_MEMORY_SCOPE_AGENT);
}
static __device__ __forceinline__ unsigned coh_load4(const unsigned* p) {
    return __hip_atomic_load(p, __ATOMIC_RELAXED, __HIP_MEMORY_SCOPE_AGENT);
}
static __device__ __forceinline__ void coh_store4(unsigned* p, unsigned v) {
    __hip_atomic_store(p, v, __ATOMIC_RELAXED, __HIP_MEMORY_SCOPE_AGENT);
}

// ---------------- x fp32 -> bf16 ----------------
__global__ __launch_bounds__(256) void convert_x(const float* __restrict__ x,
                                                 unsigned short* __restrict__ xb) {
    size_t i = ((size_t)blockIdx.x * 256 + threadIdx.x) * 4;
    float4 v = *(const float4*)(x + i);
    ushort4 o;
    o.x = f2bf(v.x); o.y = f2bf(v.y); o.z = f2bf(v.z); o.w = f2bf(v.w);
    *(ushort4*)(xb + i) = o;
}

// ---------------- persistent recurrence kernel (pre-GEMM fused, pipelined) -----
// 64 blocks x 256 threads. Block bx: c=bx&15 (cols 64c..64c+64), r=bx>>4
// (rows 16r..16r+16). Wave w owns K range [256w..256w+256); Wh AND Wx slices
// in REGISTERS. h chunks (16B) A-frag layout: unit16 = r*2048 + ks*64 + lkq*16 + m.
// Per step t: [top, PRE-POLL] pre[t+1] = x[t+1]@Wx (8 MFMA from regs; hidden in
// poll slack, wave-private parity ldsPre) -> poll (16 producer wave-flags) ->
// 8 sc1 dwordx4 h loads (one vmcnt window) -> 32 h-MFMA -> partials to parity
// ldsR -> ONE barrier -> 4-wave reduce + pre[t] + tanh -> coherent 8B store ->
// per-wave vmcnt drain -> wave flag -> [POST-FLAG] issue x[t+2] loads (land
// during next step's poll; never on the critical chain).
// h triple-buffered (R9 skew<=2 safety argument unchanged).
__global__ __launch_bounds__(256, 1) void rnn_persistent(const float* __restrict__ Wh,
                                                         const float* __restrict__ Wx,
                                                         const float* __restrict__ bias,
                                                         const unsigned short* __restrict__ xb,
                                                         unsigned short* __restrict__ hbuf,
                                                         unsigned* __restrict__ flags) {
    __shared__ float ldsR[2][4][16 * 68];            // 34816 B: cross-wave partials
    __shared__ float ldsPre[2][4][16 * 20];          // 10240 B: pre tiles (wave-private)
    const int bx = blockIdx.x;
    const int c = bx & 15, r = bx >> 4;
    const int tid = threadIdx.x;
    const int w = tid >> 6, lane = tid & 63;
    const int l15 = lane & 15, lkq = lane >> 4;
    const int p = (lane >> 4) & 1, q = lane >> 5;
    const int m = l15;

    // One-time: Wh B-fragments (k in wave range, cols 64c..64c+64) -> regs.
    bf16x8 bfr[8][4];
#pragma unroll
    for (int ksl = 0; ksl < 8; ++ksl)
#pragma unroll
        for (int nt = 0; nt < 4; ++nt) {
            union { unsigned short s[8]; bf16x8 h; } u;
            int k0 = w * 256 + ksl * 32 + lkq * 8;
            int col = c * 64 + nt * 16 + l15;
#pragma unroll
            for (int j = 0; j < 8; ++j)
                u.s[j] = f2bf(Wh[(size_t)(k0 + j) * HID + col]);
            bfr[ksl][nt] = u.h;
        }

    // One-time: Wx B-frags for wave w's 16 cols (full K=256) -> REGISTERS.
    bf16x8 bfx[8];
    {
        int col = c * 64 + w * 16 + l15;
#pragma unroll
        for (int ksl = 0; ksl < 8; ++ksl) {
            union { unsigned short s[8]; bf16x8 h; } u;
            int k0 = ksl * 32 + lkq * 8;
#pragma unroll
            for (int j = 0; j < 8; ++j)
                u.s[j] = f2bf(Wx[(size_t)(k0 + j) * HID + col]);
            bfx[ksl] = u.h;
        }
    }
    const float bb = bias[c * 64 + w * 16 + l15];

    // Bootstrap: pre[0] -> ldsPre[0], pre[1] -> ldsPre[1].
#pragma unroll
    for (int tt = 0; tt < 2; ++tt) {
        f32x4 pacc = {};
#pragma unroll
        for (int ksl = 0; ksl < 8; ++ksl) {
            bf16x8 a = *(const bf16x8*)(xb + ((size_t)tt * 64 + 16 * r + l15) * 256 + ksl * 32 + lkq * 8);
            pacc = __builtin_amdgcn_mfma_f32_16x16x32_bf16(a, bfx[ksl], pacc, 0, 0, 0);
        }
#pragma unroll
        for (int reg = 0; reg < 4; ++reg)
            ldsPre[tt][w][(lkq * 4 + reg) * 20 + l15] = pacc[reg] + bb;
    }
    // Preload x[2] A-frags (consumed at top of iter t=1 to build pre[2]).
    i32x4 xl[8];
    {
        const unsigned short* xbase = xb + ((size_t)2 * 64 + 16 * r + l15) * 256 + lkq * 8;
#pragma unroll
        for (int ksl = 0; ksl < 8; ++ksl)
            xl[ksl] = *(const i32x4*)(xbase + ksl * 32);
    }

    char* hb = (char*)hbuf;               // 3 buffers x 128 KB
    const char* hc = hb + 131072;         // read  at t=1 (h_1)
    char*       hn = hb + 2 * 131072;     // write at t=1 (h_2)
    char*       hx = hb;                  // write at t=2

    // This thread's h-store unit (8B): chunk (ks=2c+(w>>1), lkq=2(w&1)+p, m), half q
    const size_t st_unit8 =
        2 * ((size_t)r * 2048 + (size_t)(2 * c + (w >> 1)) * 64 + (2 * (w & 1) + p) * 16 + m) + q;

    const int myFlag = (bx << 2) + w;
    const int pollIdx = r * 64 + 16 * w + l15;   // 16 wave-flags of 4 producer blocks

    // t = 0: h1 = tanh(pre[0]) (h0 == 0) -> buf1.
    {
        union { ushort4 s; ull u; } hv;
        const float* P = &ldsPre[0][w][m * 20 + 8 * p + 4 * q];
        hv.s.x = f2bf(tanhf(P[0]));
        hv.s.y = f2bf(tanhf(P[1]));
        hv.s.z = f2bf(tanhf(P[2]));
        hv.s.w = f2bf(tanhf(P[3]));
        coh_store8((ull*)(hb + 131072) + st_unit8, hv.u);
        __builtin_amdgcn_fence(__ATOMIC_RELEASE, "workgroup");   // per-wave vmcnt drain
        if (lane == 0) coh_store4(&flags[myFlag], 1u);
    }

    for (int t = 1; t <= 510; ++t) {
        // [PRE-POLL, hidden in poll slack] pre[t+1] from xl (regs, loaded last
        // iter) -> wave-private parity ldsPre. No h dependence, no barrier.
        if (t <= 509) {
            f32x4 pacc = {};
#pragma unroll
            for (int ksl = 0; ksl < 8; ++ksl) {
                union { i32x4 i; bf16x8 h; } av; av.i = xl[ksl];
                pacc = __builtin_amdgcn_mfma_f32_16x16x32_bf16(av.h, bfx[ksl], pacc, 0, 0, 0);
            }
#pragma unroll
            for (int reg = 0; reg < 4; ++reg)
                ldsPre[(t + 1) & 1][w][(lkq * 4 + reg) * 20 + l15] = pacc[reg] + bb;
        }

        // Early-start poll: wave w waits only for its k-range producers.
        {
            const unsigned tt = (unsigned)t;
            for (;;) {
                unsigned v = coh_load4(&flags[pollIdx]);
                if (__ballot(v >= tt) == ~0ull) break;
                __builtin_amdgcn_s_sleep(1);
            }
        }

        // h import: 8 x 16B agent-coherent loads, ALL in flight, one window.
        i32x4 a[8];
        const char* abase = hc + ((size_t)r * 2048 + (size_t)(8 * w) * 64 + lane) * 16;
#pragma unroll
        for (int ksl = 0; ksl < 8; ++ksl)
            asm volatile("global_load_dwordx4 %0, %1, off sc1"
                         : "=v"(a[ksl])
                         : "v"((const void*)(abase + (size_t)ksl * 1024)));
        asm volatile("s_waitcnt vmcnt(0)" ::: "memory");
        __builtin_amdgcn_sched_barrier(0);

        f32x4 acc0 = {}, acc1 = {}, acc2 = {}, acc3 = {};
#pragma unroll
        for (int ksl = 0; ksl < 8; ++ksl) {
            union { i32x4 i; bf16x8 h; } av; av.i = a[ksl];
            acc0 = __builtin_amdgcn_mfma_f32_16x16x32_bf16(av.h, bfr[ksl][0], acc0, 0, 0, 0);
            acc1 = __builtin_amdgcn_mfma_f32_16x16x32_bf16(av.h, bfr[ksl][1], acc1, 0, 0, 0);
            acc2 = __builtin_amdgcn_mfma_f32_16x16x32_bf16(av.h, bfr[ksl][2], acc2, 0, 0, 0);
            acc3 = __builtin_amdgcn_mfma_f32_16x16x32_bf16(av.h, bfr[ksl][3], acc3, 0, 0, 0);
        }

        // Partial sums -> parity LDS (row = lkq*4+reg, col = nt*16+l15).
        float* R = &ldsR[t & 1][w][0];
#pragma unroll
        for (int reg = 0; reg < 4; ++reg) {
            R[(lkq * 4 + reg) * 68 + l15]      = acc0[reg];
            R[(lkq * 4 + reg) * 68 + 16 + l15] = acc1[reg];
            R[(lkq * 4 + reg) * 68 + 32 + l15] = acc2[reg];
            R[(lkq * 4 + reg) * 68 + 48 + l15] = acc3[reg];
        }

        __syncthreads();   // the ONE barrier per step (cross-wave reduce)

        // Reduce across 4 waves, add pre[t], tanh, pack, coherent 8B store.
        const int coloff = 16 * w + 8 * p + 4 * q;
        f32x4 s;
        s  = *(const f32x4*)&ldsR[t & 1][0][m * 68 + coloff];
        s += *(const f32x4*)&ldsR[t & 1][1][m * 68 + coloff];
        s += *(const f32x4*)&ldsR[t & 1][2][m * 68 + coloff];
        s += *(const f32x4*)&ldsR[t & 1][3][m * 68 + coloff];
        const float* P = &ldsPre[t & 1][w][m * 20 + 8 * p + 4 * q];
        union { ushort4 st; ull u; } hv;
        hv.st.x = f2bf(tanhf(s[0] + P[0]));
        hv.st.y = f2bf(tanhf(s[1] + P[1]));
        hv.st.z = f2bf(tanhf(s[2] + P[2]));
        hv.st.w = f2bf(tanhf(s[3] + P[3]));
        coh_store8((ull*)hn + st_unit8, hv.u);

        __builtin_amdgcn_fence(__ATOMIC_RELEASE, "workgroup");   // per-wave vmcnt drain
        if (t < 510 && lane == 0) coh_store4(&flags[myFlag], (unsigned)(t + 1));

        // [POST-FLAG] issue x[t+2] loads: land during next step's poll window.
        if (t <= 508) {
            const unsigned short* xbase = xb + ((size_t)(t + 2) * 64 + 16 * r + l15) * 256 + lkq * 8;
#pragma unroll
            for (int ksl = 0; ksl < 8; ++ksl)
                xl[ksl] = *(const i32x4*)(xbase + ksl * 32);
        }

        // rotate triple buffer
        const char* tmp = hc; hc = hn; hn = hx; hx = (char*)tmp;
    }
    // h_511 (== H[-2]) is in buf1; kernel end = implicit device release.
}

// ---------------- y = h_final @ W2 + b2 (h in A-frag chunk layout) ----------
__global__ __launch_bounds__(256) void out_gemm(const unsigned short* __restrict__ hfin,
                                                const float* __restrict__ W2,
                                                const float* __restrict__ b2,
                                                float* __restrict__ out) {
    int b = blockIdx.x;        // batch row, 64
    int j = threadIdx.x;       // out col, 256
    int r = b >> 4, m = b & 15;
    float acc = b2[j];
    for (int ks = 0; ks < 32; ++ks) {
#pragma unroll
        for (int lkq = 0; lkq < 4; ++lkq) {
            const unsigned short* ch =
                hfin + ((size_t)(r * 2048 + ks * 64 + lkq * 16 + m)) * 8;
            int k0 = ks * 32 + lkq * 8;
#pragma unroll
            for (int jj = 0; jj < 8; ++jj)
                acc = fmaf(bf2f(ch[jj]), W2[(size_t)(k0 + jj) * DOUT + j], acc);
        }
    }
    out[(size_t)b * DOUT + j] = acc;
}

extern "C" void kernel_launch(void* const* d_in, const int* in_sizes, int n_in,
                              void* d_out, int out_size, void* d_ws, size_t ws_size,
                              hipStream_t stream) {
    const float* x  = (const float*)d_in[0];
    const float* Wx = (const float*)d_in[1];
    const float* Wh = (const float*)d_in[2];
    const float* b  = (const float*)d_in[3];
    const float* W2 = (const float*)d_in[4];
    const float* b2 = (const float*)d_in[5];
    float* out = (float*)d_out;

    // workspace carve (~17 MB)
    char* ws = (char*)d_ws;
    unsigned*       flags = (unsigned*)ws;                          // 1 KB (256 wave-flags)
    unsigned short* hbuf  = (unsigned short*)(ws + 4096);           // 3 x 128 KB
    unsigned short* xb    = (unsigned short*)(ws + 4096 + 393216);  // 16 MB bf16 x

    (void)hipMemsetAsync(flags, 0, 4096, stream);
    convert_x<<<8192, 256, 0, stream>>>(x, xb);
    rnn_persistent<<<NBLK, 256, 0, stream>>>(Wh, Wx, b, xb, hbuf, flags);
    out_gemm<<<64, 256, 0, stream>>>(hbuf + 65536, W2, b2, out);
}